// Round 3
// baseline (165.352 us; speedup 1.0000x reference)
//
#include <hip/hip_runtime.h>
#include <math.h>

// YOLO box decode: (32, 3*85, 52, 52) -> (32*3*52*52, 85)
// R12: MAX TIME-CONTIGUOUS READ BURSTS. Falsification matrix R2-R11: instr
// shape, granule (416B/1KB), occupancy (27/54%), NT/cached, barriers, MLP
// all FLAT at ~2.4 TB/s fabric while linear 1:1 copy does 6.3. Last standing
// difference: reads are 85 strided streams with <=1 KB time-contiguous
// bursts. This version stretches each channel's burst to 2704 B (a full
// channel quarter): tiles of 676 spatial (NTILE=4, all identical), each
// (wave,channel) issues 3 back-to-back full-wave dwordx4 loads covering one
// contiguous 2.7 KB span. 33 f4 regs/thread (~200 VGPR, 1 blk/CU -- 25%
// occupancy proven harmless in R9). Drain: 11 chunks of [64 sp x 85 ch] via
// LDS, contiguous NT f4 store runs. Chunk loop fully unrolled so register
// indices stay compile-time (no scratch).

typedef float nat_float4 __attribute__((ext_vector_type(4)));

#define NSPAT   2704          // 52*52
#define NCH     85            // 5 + 80 classes
#define NSLAB   96            // 32 batches * 3 anchors
#define NTILE   4             // tiles per slab, all identical
#define TILEF4  169           // f4 per channel per tile
#define TILESP  676           // spatial per tile
#define TPB     512           // 8 waves
#define CHUNK   64            // spatial rows per drain pass
#define RUNF4   676           // f4 per channel row (2704/4)
#define SLABF4  (NCH * NSPAT / 4)  // 57460 f4 per slab

__global__ __launch_bounds__(TPB) void yolo_decode_kernel(
    const float* __restrict__ in, float* __restrict__ out) {
  __shared__ __align__(16) float tile[CHUNK * NCH];   // 21760 B

  const int t    = threadIdx.x;
  const int w    = t >> 6;                 // wave 0..7
  const int q    = t & 63;                 // f4 offset within run (== lane)
  const int slab = blockIdx.x / NTILE;     // b*3 + a
  const int tt   = blockIdx.x - slab * NTILE;
  const int a    = slab % 3;               // ANCHOR_MASK = [0,1,2]

  const float aw = (a == 0) ? 10.0f : (a == 1) ? 16.0f : 33.0f;
  const float ah = (a == 0) ? 13.0f : (a == 1) ? 30.0f : 23.0f;

  // ---- Phase 1: per (wave,channel) 3 back-to-back full-wave dwordx4 loads
  //      = one contiguous 2704 B burst per channel ----
  nat_float4 v[11][3];
  const nat_float4* src = (const nat_float4*)in
      + (long)slab * SLABF4 + tt * TILEF4 + q;
  #pragma unroll
  for (int k = 0; k < 11; ++k) {
    const int c = w + 8 * k;               // wave w owns channels w, w+8, ...
    if (c < NCH) {
      const nat_float4* s = src + (long)c * RUNF4;
      #pragma unroll
      for (int j = 0; j < 3; ++j)
        if (q + 64 * j < TILEF4) v[k][j] = s[64 * j];   // j=2 only for q<41
    }
  }

  // ---- Phase 2: transform in registers. c<5 lives only in v[0] of waves 0..4 ----
  if (w < 5) {
    #pragma unroll
    for (int j = 0; j < 3; ++j) {
      if (q + 64 * j < TILEF4) {
        #pragma unroll
        for (int r = 0; r < 4; ++r) {
          const int sg = tt * TILESP + 4 * (q + 64 * j) + r;  // h*52 + w
          float x = v[0][j][r];
          if (w == 0)      x = 1.0f / (1.0f + __expf(-x)) + (float)(sg % 52);
          else if (w == 1) x = 1.0f / (1.0f + __expf(-x)) + (float)(sg / 52);
          else if (w == 2) x = __expf(x * (1.0f / 416.0f)) * aw;
          else if (w == 3) x = __expf(x * (1.0f / 416.0f)) * ah;
          else             x = 1.0f / (1.0f + __expf(-x));
          v[0][j][r] = x;
        }
      }
    }
  }

  // ---- Phase 3: 11 transpose/drain chunks of 64 spatial rows (last = 36) ----
  // Chunk p consumes f4 index 16p+ql (ql = q&15) from register j = p>>2 of
  // lanes with q>>4 == p&3. Fully unrolled: all v[][] indices compile-time.
  #pragma unroll
  for (int p = 0; p < 11; ++p) {
    const int jj = p >> 2;                 // compile-time per unrolled iter
    if ((q >> 4) == (p & 3) && (q + 64 * jj < TILEF4)) {
      const int ql = q & 15;               // chunk row group 4*ql..4*ql+3
      #pragma unroll
      for (int k = 0; k < 11; ++k) {
        const int c = w + 8 * k;
        if (c < NCH) {
          tile[(4 * ql + 0) * NCH + c] = v[k][jj].x;
          tile[(4 * ql + 1) * NCH + c] = v[k][jj].y;
          tile[(4 * ql + 2) * NCH + c] = v[k][jj].z;
          tile[(4 * ql + 3) * NCH + c] = v[k][jj].w;
        }
      }
    }
    __syncthreads();

    int rows = TILESP - p * CHUNK;
    if (rows > CHUNK) rows = CHUNK;        // 64, last chunk 36
    const int nf4 = rows * NCH / 4;        // 1360 / 765
    const nat_float4* s4 = (const nat_float4*)tile;
    nat_float4* dst = (nat_float4*)out + (long)slab * SLABF4
        + ((long)(tt * TILESP + p * CHUNK) * NCH) / 4;
    for (int j = t; j < nf4; j += TPB)
      __builtin_nontemporal_store(s4[j], dst + j);
    __syncthreads();
  }
}

extern "C" void kernel_launch(void* const* d_in, const int* in_sizes, int n_in,
                              void* d_out, int out_size, void* d_ws, size_t ws_size,
                              hipStream_t stream) {
  const float* in = (const float*)d_in[0];
  float* out = (float*)d_out;
  yolo_decode_kernel<<<NSLAB * NTILE, TPB, 0, stream>>>(in, out);
}

// Round 4
// 164.958 us; speedup vs baseline: 1.0024x; 1.0024x over previous
//
#include <hip/hip_runtime.h>
#include <math.h>

// YOLO box decode: (32, 3*85, 52, 52) -> (32*3*52*52, 85)
// R13: READ/WRITE TEMPORAL MIXING. R2-R12 matrix (shape, granule 0.4/1/2.7KB,
// occupancy 14-54%, NT/cached, barriers, MLP) ALL FLAT at ~2.4 TB/s. The one
// thing never varied: every version does all-reads -> barrier -> all-writes,
// and __syncthreads() emits s_waitcnt vmcnt(0) before s_barrier (m97 drain),
// so the machine oscillates between pure-read and pure-write phases, paying
// each direction serially at ~one-directional rate: 88/3.15 + 88/3.15 = 56us
// = the measured plateau. Copy kernels (6.3 TB/s) keep both directions in
// flight. Fix (T3/T4 idiom): 4-tile pipeline per block; issue tile k+1 loads
// BEFORE draining tile k; raw __builtin_amdgcn_s_barrier() with ONLY
// lgkmcnt(0) so prefetch loads + NT stores stay in flight across barriers.
// 96 slabs x 13 parts = 1248 uniform blocks (4.9/CU), 5 waves, 17.7KB LDS.

typedef float nat_float4 __attribute__((ext_vector_type(4)));
typedef float nat_float2 __attribute__((ext_vector_type(2)));

#define NSPAT   2704          // 52*52
#define NCH     85
#define NSLAB   96            // 32 batches * 3 anchors
#define TPS     13            // block-parts per slab
#define DEPTH   4             // tiles per block (pipeline depth)
#define TSP     52            // spatial per tile
#define TPB     320           // 5 waves
#define CPW     17            // channels per wave
#define TF4     1105          // f4 per tile (52*85/4)
#define SLABSZ  (NCH * NSPAT) // floats per slab

#define BAR() do { asm volatile("s_waitcnt lgkmcnt(0)" ::: "memory"); \
                   __builtin_amdgcn_s_barrier(); } while (0)

__global__ __launch_bounds__(TPB) void yolo_decode_kernel(
    const float* __restrict__ in, float* __restrict__ out) {
  __shared__ __align__(16) float tile[TSP * NCH];   // 17,680 B

  const int t    = threadIdx.x;
  const int lane = t & 63;
  const int w    = t >> 6;                  // 0..4
  const int slab = blockIdx.x / TPS;        // b*3 + a
  const int part = blockIdx.x - slab * TPS;
  const int a    = slab % 3;                // ANCHOR_MASK = [0,1,2]

  const float aw = (a == 0) ? 10.0f : (a == 1) ? 16.0f : 33.0f;
  const float ah = (a == 0) ? 13.0f : (a == 1) ? 30.0f : 23.0f;

  const int  sbase = part * (DEPTH * TSP);  // 208*part, multiple of 52
  const int  c0    = w * CPW;
  const bool act   = (lane < 26);           // 26 lanes x dwordx2 = 52 floats

  const float* src = in + (long)slab * SLABSZ + (long)c0 * NSPAT
                     + sbase + 2 * lane;

  nat_float2 A[CPW], B[CPW];

  // issue 17 loads for tile k into register set R (contiguous 208 B runs)
  auto LOADSET = [&](nat_float2 (&R)[CPW], int k) {
    if (act) {
      #pragma unroll
      for (int j = 0; j < CPW; ++j)
        R[j] = *(const nat_float2*)(src + j * NSPAT + k * TSP);
    }
  };

  // transform (wave 0 holds channels 0..4) + stage tile k into LDS [s][c]
  auto XS = [&](nat_float2 (&R)[CPW], int k) {
    if (act) {
      if (w == 0) {
        #pragma unroll
        for (int j = 0; j < 5; ++j) {
          #pragma unroll
          for (int j2 = 0; j2 < 2; ++j2) {
            float x = R[j][j2];
            if (j == 0)      x = 1.0f/(1.0f+__expf(-x)) + (float)(2*lane + j2);
            else if (j == 1) x = 1.0f/(1.0f+__expf(-x)) + (float)(4*part + k);
            else if (j == 2) x = __expf(x * (1.0f/416.0f)) * aw;
            else if (j == 3) x = __expf(x * (1.0f/416.0f)) * ah;
            else             x = 1.0f/(1.0f+__expf(-x));
            R[j][j2] = x;
          }
        }
      }
      const int sl = 2 * lane;              // stride 170 dw -> 2-way (free)
      #pragma unroll
      for (int j = 0; j < CPW; ++j) {
        const int c = c0 + j;
        tile[sl * NCH + c]       = R[j].x;
        tile[(sl + 1) * NCH + c] = R[j].y;
      }
    }
  };

  // contiguous 17.7 KB NT store run for tile k (fixed trip count)
  auto DRAIN = [&](int k) {
    const nat_float4* s4 = (const nat_float4*)tile;
    nat_float4* dst = (nat_float4*)out + (long)slab * (SLABSZ / 4)
                      + 4420L * part + 1105L * k;
    #pragma unroll
    for (int r = 0; r < 4; ++r) {
      const int j = t + r * TPB;
      if (j < TF4) __builtin_nontemporal_store(s4[j], dst + j);
    }
  };

  // ---- depth-4 pipeline: loads(k+1) in flight across drain(k) ----
  LOADSET(A, 0);
  LOADSET(B, 1); XS(A, 0); BAR(); DRAIN(0); BAR();
  LOADSET(A, 2); XS(B, 1); BAR(); DRAIN(1); BAR();
  LOADSET(B, 3); XS(A, 2); BAR(); DRAIN(2); BAR();
                 XS(B, 3); BAR(); DRAIN(3);
}

extern "C" void kernel_launch(void* const* d_in, const int* in_sizes, int n_in,
                              void* d_out, int out_size, void* d_ws, size_t ws_size,
                              hipStream_t stream) {
  const float* in = (const float*)d_in[0];
  float* out = (float*)d_out;
  yolo_decode_kernel<<<NSLAB * TPS, TPB, 0, stream>>>(in, out);
}